// Round 1
// 331.264 us; speedup vs baseline: 1.1368x; 1.1368x over previous
//
#include <hip/hip_runtime.h>
#include <math.h>

#define NCH 64
#define NB 8
#define RSEL 8
#define SPATIAL 110592          // 48*48*48
#define S4 27648                // SPATIAL/4 float4s per channel
#define PARTS 4                 // split-K partial blocks per channel map
#define CHUNK4 (S4 / PARTS)     // 6912 float4s per partial block
#define ITERS (CHUNK4 / 256)    // 27 float4s per thread
#define BATCH 9                 // loads held in flight per round (27 = 3*9)

typedef float f4 __attribute__((ext_vector_type(4)));

// ---------------------------------------------------------------------------
// Kernel 1: per-(b,c) split-K partial sums. 2048 blocks = 8 blocks/CU.
// Loads batched 9 deep so ~36 VGPRs of f4 loads stay in flight per wave.
// NO device fences/atomics (R3 post-mortem: per-block agent-scope fences on
// multi-XCD gfx950 force L2 writeback/inv -> 229us pathological stall).
// At BW roofline: 216 MiB / ~6.3 TB/s ~= 36 us. UNCHANGED this round.
// ---------------------------------------------------------------------------
__global__ __launch_bounds__(256) void mean_kernel(const float* __restrict__ x,
                                                   float* __restrict__ partials) {
    const int bc   = blockIdx.x >> 2;   // 0..511  (b*64 + c)
    const int part = blockIdx.x & 3;
    const f4* p = (const f4*)(x + (size_t)bc * SPATIAL) + part * CHUNK4 + threadIdx.x;
    float s = 0.f;
    #pragma unroll
    for (int r = 0; r < ITERS / BATCH; ++r) {
        f4 v[BATCH];
        #pragma unroll
        for (int i = 0; i < BATCH; ++i) v[i] = p[(r * BATCH + i) * 256];
        #pragma unroll
        for (int i = 0; i < BATCH; ++i) s += (v[i].x + v[i].y) + (v[i].z + v[i].w);
    }
    // intra-wave reduction (wave = 64)
    #pragma unroll
    for (int o = 32; o >= 1; o >>= 1) s += __shfl_down(s, o, 64);
    __shared__ float ws[4];
    const int lane = threadIdx.x & 63;
    const int wv   = threadIdx.x >> 6;
    if (lane == 0) ws[wv] = s;
    __syncthreads();
    if (threadIdx.x == 0) {
        partials[blockIdx.x] = (ws[0] + ws[1]) + (ws[2] + ws[3]);
    }
}

// ---------------------------------------------------------------------------
// Kernel 2: combine partials -> means, MLP + sigmoid + top-8.
// REWORKED this round: 256 threads (4 waves, 2 batches per wave) instead of
// one wave; f4-vectorized weight-row loads issued before the partials
// combine (latency hidden); top-8 via rank-counting (64 parallel compares,
// stable lower-index-first ties == jax.lax.top_k) instead of 8x6x8 = 384
// dependency-chained butterfly shuffles.
// ---------------------------------------------------------------------------
__global__ __launch_bounds__(256) void mlp_topk_kernel(const float* __restrict__ partials,
                                                      const float* __restrict__ w1,
                                                      const float* __restrict__ b1,
                                                      const float* __restrict__ w2,
                                                      const float* __restrict__ b2,
                                                      int* __restrict__ idx_out) {
    const int t  = threadIdx.x;   // 0..255
    const int j  = t & 63;        // output channel
    const int wv = t >> 6;        // wave id 0..3
    const int ba = 2 * wv;        // this wave's batches: ba, ba+1
    const int bb = ba + 1;

    __shared__ float m[NB][NCH];
    __shared__ float h[NB][NCH];
    __shared__ float y[NB][NCH];

    // Issue layer-1 weight row loads (f4) FIRST so HBM latency hides under
    // the partials combine below.
    const f4* wr1 = (const f4*)(w1 + (size_t)j * NCH);
    f4 wvreg[16];
    #pragma unroll
    for (int q = 0; q < 16; ++q) wvreg[q] = wr1[q];
    const float bias1 = b1[j];

    // combine split-K partials -> means (512 entries, 2 per thread)
    #pragma unroll
    for (int i = 0; i < 2; ++i) {
        const int e = t + i * 256;                 // e = b*64 + c
        const float* pp = partials + (size_t)e * PARTS;
        m[e >> 6][e & 63] = ((pp[0] + pp[1]) + (pp[2] + pp[3])) * (1.0f / (float)SPATIAL);
    }
    __syncthreads();

    // layer 1: h[b][j] = leaky_relu( sum_k m[b][k] * w1[j][k] + b1[j] )
    // m[b][k] reads are wave-uniform LDS broadcasts (conflict-free).
    {
        float a0 = bias1, a1 = bias1;
        #pragma unroll
        for (int q = 0; q < 16; ++q) {
            #pragma unroll
            for (int s = 0; s < 4; ++s) {
                const float wk = ((const float*)&wvreg[q])[s];
                a0 += m[ba][q * 4 + s] * wk;
                a1 += m[bb][q * 4 + s] * wk;
            }
        }
        h[ba][j] = a0 > 0.f ? a0 : 0.01f * a0;
        h[bb][j] = a1 > 0.f ? a1 : 0.01f * a1;
    }
    // h[ba]/h[bb] are produced and consumed by the same wave, but keep the
    // barrier: 4-wave barrier is ~100 cycles, correctness risk is not worth it.
    __syncthreads();

    // layer 2: y[b][j] = sigmoid( sum_k h[b][k] * w2[j][k] + b2[j] )
    {
        const f4* wr2 = (const f4*)(w2 + (size_t)j * NCH);
        #pragma unroll
        for (int q = 0; q < 16; ++q) wvreg[q] = wr2[q];
        const float bias2 = b2[j];
        float a0 = bias2, a1 = bias2;
        #pragma unroll
        for (int q = 0; q < 16; ++q) {
            #pragma unroll
            for (int s = 0; s < 4; ++s) {
                const float wk = ((const float*)&wvreg[q])[s];
                a0 += h[ba][q * 4 + s] * wk;
                a1 += h[bb][q * 4 + s] * wk;
            }
        }
        y[ba][j] = 1.0f / (1.0f + expf(-a0));
        y[bb][j] = 1.0f / (1.0f + expf(-a1));
    }
    __syncthreads();

    // top-8 per batch row by rank-counting. rank = #{k: y[k]>y[j] or
    // (y[k]==y[j] and k<j)} reproduces descending stable order with
    // lower-index-first ties — identical to jax.lax.top_k.
    #pragma unroll
    for (int i = 0; i < 2; ++i) {
        const int e  = t + i * 256;                // e = b*64 + j
        const int eb = e >> 6;
        const int ej = e & 63;
        const float mine = y[eb][ej];
        int rank = 0;
        #pragma unroll
        for (int k = 0; k < NCH; ++k) {
            const float v = y[eb][k];              // wave-uniform broadcast
            rank += (int)((v > mine) | ((v == mine) & (k < ej)));
        }
        if (rank < RSEL) idx_out[eb * RSEL + rank] = ej;
    }
}

// ---------------------------------------------------------------------------
// Kernel 3: gather selected channels. grid = (27, 64). Reads mostly hit
// L2/L3 (x just streamed, 226.5 MB < 256 MB L3); nontemporal stores keep
// the never-re-read output from evicting x. UNCHANGED this round.
// ---------------------------------------------------------------------------
__global__ __launch_bounds__(256) void gather_kernel(const float* __restrict__ x,
                                                     const int* __restrict__ idx,
                                                     float* __restrict__ out) {
    const int pair = blockIdx.y;          // 0..63  (b*8 + r)
    const int b    = pair >> 3;
    const int ch   = idx[pair];
    const f4* src = (const f4*)(x + (size_t)(b * NCH + ch) * SPATIAL);
    f4*       dst = (f4*)(out + (size_t)pair * SPATIAL);
    const int base = blockIdx.x * 1024 + threadIdx.x;
    #pragma unroll
    for (int i = 0; i < 4; ++i) {
        f4 v = src[base + i * 256];
        __builtin_nontemporal_store(v, &dst[base + i * 256]);
    }
}

extern "C" void kernel_launch(void* const* d_in, const int* in_sizes, int n_in,
                              void* d_out, int out_size, void* d_ws, size_t ws_size,
                              hipStream_t stream) {
    const float* x  = (const float*)d_in[0];
    const float* w1 = (const float*)d_in[1];
    const float* b1 = (const float*)d_in[2];
    const float* w2 = (const float*)d_in[3];
    const float* b2 = (const float*)d_in[4];
    float* out = (float*)d_out;

    float* partials = (float*)d_ws;                                     // 2048 floats
    int*   idx      = (int*)((char*)d_ws + NB * NCH * PARTS * sizeof(float)); // 64 ints

    mean_kernel<<<dim3(NB * NCH * PARTS), dim3(256), 0, stream>>>(x, partials);
    mlp_topk_kernel<<<dim3(1), dim3(256), 0, stream>>>(partials, w1, b1, w2, b2, idx);
    gather_kernel<<<dim3(S4 / 1024, NB * RSEL), dim3(256), 0, stream>>>(x, idx, out);
}

// Round 2
// 329.736 us; speedup vs baseline: 1.1421x; 1.0046x over previous
//
#include <hip/hip_runtime.h>
#include <math.h>

#define NCH 64
#define NB 8
#define RSEL 8
#define SPATIAL 110592          // 48*48*48
#define S4 27648                // SPATIAL/4 float4s per channel
#define PARTS 4                 // split-K partial blocks per channel map
#define CHUNK4 (S4 / PARTS)     // 6912 float4s per partial block
#define ITERS (CHUNK4 / 256)    // 27 float4s per thread
#define BATCH 9                 // loads held in flight per round (27 = 3*9)

typedef float f4 __attribute__((ext_vector_type(4)));

// ---------------------------------------------------------------------------
// Kernel 1: per-(b,c) split-K partial sums. 2048 blocks = 8 blocks/CU.
// Loads batched 9 deep so ~36 VGPRs of f4 loads stay in flight per wave.
// NO device fences/atomics (R3 post-mortem: per-block agent-scope fences on
// multi-XCD gfx950 force L2 writeback/inv -> 229us pathological stall).
// At BW roofline: 216 MiB compulsory read / ~6.3 TB/s ~= 36 us. UNCHANGED.
// ---------------------------------------------------------------------------
__global__ __launch_bounds__(256) void mean_kernel(const float* __restrict__ x,
                                                   float* __restrict__ partials) {
    const int bc   = blockIdx.x >> 2;   // 0..511  (b*64 + c)
    const int part = blockIdx.x & 3;
    const f4* p = (const f4*)(x + (size_t)bc * SPATIAL) + part * CHUNK4 + threadIdx.x;
    float s = 0.f;
    #pragma unroll
    for (int r = 0; r < ITERS / BATCH; ++r) {
        f4 v[BATCH];
        #pragma unroll
        for (int i = 0; i < BATCH; ++i) v[i] = p[(r * BATCH + i) * 256];
        #pragma unroll
        for (int i = 0; i < BATCH; ++i) s += (v[i].x + v[i].y) + (v[i].z + v[i].w);
    }
    // intra-wave reduction (wave = 64)
    #pragma unroll
    for (int o = 32; o >= 1; o >>= 1) s += __shfl_down(s, o, 64);
    __shared__ float ws[4];
    const int lane = threadIdx.x & 63;
    const int wv   = threadIdx.x >> 6;
    if (lane == 0) ws[wv] = s;
    __syncthreads();
    if (threadIdx.x == 0) {
        partials[blockIdx.x] = (ws[0] + ws[1]) + (ws[2] + ws[3]);
    }
}

// ---------------------------------------------------------------------------
// Kernel 2 (fused, NEW this round): every gather block redundantly computes
// the 64-wide MLP + sigmoid + rank-count top-8 for ITS OWN (b, r) pair from
// the split-K partials, then gathers. Removes the former 1-block mlp_topk
// kernel (a whole-GPU serialization bubble) and its launch gap. MLP work is
// wave-0-only, ~8K MACs x2 per block; partials (1 KB) and weights (32 KB)
// are L2/L1-hot after the first block per XCD/CU, and the redundant compute
// overlaps with other resident blocks' gather I/O (6-8 blocks/CU).
// Rank-counting reproduces jax.lax.top_k exactly: descending, stable,
// lower index first on ties.
// ---------------------------------------------------------------------------
__global__ __launch_bounds__(256) void mlp_gather_kernel(const float* __restrict__ x,
                                                         const float* __restrict__ partials,
                                                         const float* __restrict__ w1,
                                                         const float* __restrict__ b1,
                                                         const float* __restrict__ w2,
                                                         const float* __restrict__ b2,
                                                         float* __restrict__ out) {
    const int pair = blockIdx.y;          // 0..63  (b*8 + r)
    const int b    = pair >> 3;
    const int r    = pair & 7;
    const int t    = threadIdx.x;

    __shared__ float m_s[NCH];
    __shared__ float h_s[NCH];
    __shared__ float y_s[NCH];
    __shared__ int   ch_s;

    f4 wreg[16];
    float bias = 0.f;
    if (t < NCH) {
        // issue weight-row + partials loads together; latency overlaps
        const f4* wr = (const f4*)(w1 + (size_t)t * NCH);
        #pragma unroll
        for (int q = 0; q < 16; ++q) wreg[q] = wr[q];
        bias = b1[t];
        const f4 pv = ((const f4*)partials)[b * NCH + t];
        m_s[t] = ((pv.x + pv.y) + (pv.z + pv.w)) * (1.0f / (float)SPATIAL);
    }
    __syncthreads();

    if (t < NCH) {
        float acc = bias;
        #pragma unroll
        for (int q = 0; q < 16; ++q) {
            acc += m_s[4 * q + 0] * wreg[q].x + m_s[4 * q + 1] * wreg[q].y +
                   m_s[4 * q + 2] * wreg[q].z + m_s[4 * q + 3] * wreg[q].w;
        }
        h_s[t] = acc > 0.f ? acc : 0.01f * acc;
    }
    __syncthreads();

    if (t < NCH) {
        const f4* wr = (const f4*)(w2 + (size_t)t * NCH);
        #pragma unroll
        for (int q = 0; q < 16; ++q) wreg[q] = wr[q];
        float acc = b2[t];
        #pragma unroll
        for (int q = 0; q < 16; ++q) {
            acc += h_s[4 * q + 0] * wreg[q].x + h_s[4 * q + 1] * wreg[q].y +
                   h_s[4 * q + 2] * wreg[q].z + h_s[4 * q + 3] * wreg[q].w;
        }
        y_s[t] = 1.0f / (1.0f + expf(-acc));
    }
    __syncthreads();

    if (t < NCH) {
        const float mine = y_s[t];
        int rank = 0;
        #pragma unroll
        for (int k = 0; k < NCH; ++k) {
            const float v = y_s[k];                // wave-uniform LDS broadcast
            rank += (int)((v > mine) | ((v == mine) & (k < t)));
        }
        if (rank == r) ch_s = t;                   // ranks are a permutation: exactly one writer
    }
    __syncthreads();

    const int ch = ch_s;
    const f4* src = (const f4*)(x + (size_t)(b * NCH + ch) * SPATIAL);
    f4*       dst = (f4*)(out + (size_t)pair * SPATIAL);
    const int base = blockIdx.x * 1024 + t;
    #pragma unroll
    for (int i = 0; i < 4; ++i) {
        f4 v = src[base + i * 256];                // mostly L3-hit: x just streamed
        __builtin_nontemporal_store(v, &dst[base + i * 256]);
    }
}

extern "C" void kernel_launch(void* const* d_in, const int* in_sizes, int n_in,
                              void* d_out, int out_size, void* d_ws, size_t ws_size,
                              hipStream_t stream) {
    const float* x  = (const float*)d_in[0];
    const float* w1 = (const float*)d_in[1];
    const float* b1 = (const float*)d_in[2];
    const float* w2 = (const float*)d_in[3];
    const float* b2 = (const float*)d_in[4];
    float* out = (float*)d_out;

    float* partials = (float*)d_ws;   // 2048 floats

    mean_kernel<<<dim3(NB * NCH * PARTS), dim3(256), 0, stream>>>(x, partials);
    mlp_gather_kernel<<<dim3(S4 / 1024, NB * RSEL), dim3(256), 0, stream>>>(
        x, partials, w1, b1, w2, b2, out);
}